// Round 6
// baseline (238.020 us; speedup 1.0000x reference)
//
#include <hip/hip_runtime.h>
#include <hip/hip_bf16.h>

// Gathered skinny GEMM: out[b, r] = sum_d x[b,d] * w[indices[r], d]
//   x: [32][4096] f32, w: [11008][4096] f32, indices: [4403] i32,
//   out: [32][4403] f32
//
// R6: R5's p1 (~35us est.) was latency-bound: W-loads staged in VGPRs cap
// memory-level parallelism at ~2KB in flight/CU vs ~9.2KB needed to cover
// ~900cyc HBM latency at the CU's 10.2 B/cyc share. Fix: stage W via
// __builtin_amdgcn_global_load_lds (width=16) - in-flight bytes live in the
// vmcnt queue + LDS, zero VGPR cost -> each wave posts its full 16KB chunk
// (16 DMAs) before a single drain. 8 waves/CU x 16KB = 128KB in flight.
// DMA lands at wave-uniform-base + lane*16, which IS the fragment order ->
// readback is conflict-free ds_read_b128. Block = 4 ks-waves of one r-tile;
// LDS-reduce -> 4 partial planes (2.8MB round trip). ~197us of dur_us is
// fixed harness overhead (ws poison fills); kernel budget is the rest.

#define D_MODEL   4096
#define REMAINED  4403
#define BATCH     32
#define KSPLIT    16
#define KCHUNK    (D_MODEL / KSPLIT)      // 256 floats per wave
#define KSTEPS    (KCHUNK / 32)           // 8 MFMA k-steps per wave
#define RT16      ((REMAINED + 15) / 16)  // 276 r-tiles
#define RSLOTS    (RT16 * 16)             // 4416 padded rows
#define BLOCK     256
#define QSPLIT    4                       // ks-groups (planes); 4 waves/blk
#define GRID1     (RT16 * QSPLIT)         // 1104 blocks

typedef __attribute__((ext_vector_type(8))) short  short8;   // 8 bf16
typedef __attribute__((ext_vector_type(4))) float  floatx4;  // 4 fp32 acc

// ws layout: [0, 256KB) x_bf16 [32][4096]; then partial[QSPLIT][BATCH][RSLOTS]
#define XB_ELEMS   (BATCH * D_MODEL)                 // 131072
#define PART_OFF   (XB_ELEMS * 2)                    // bytes: 256 KB

// async global->LDS, 16B per lane, dest = uniform base + lane*16
#define GLD_LDS(gp, lp)                                                        \
    __builtin_amdgcn_global_load_lds(                                          \
        (const __attribute__((address_space(1))) void*)(gp),                   \
        (__attribute__((address_space(3))) void*)(lp), 16, 0, 0)

// ---- p0: convert x to bf16 (RNE) ------------------------------------
__global__ __launch_bounds__(BLOCK) void p0_cvt(
    const float* __restrict__ x, __hip_bfloat16* __restrict__ xb)
{
    const int i = blockIdx.x * BLOCK + threadIdx.x;  // 4 floats each
    const float4 v = ((const float4*)x)[i];
    __hip_bfloat162* o = (__hip_bfloat162*)xb;
    o[2 * i + 0] = __float22bfloat162_rn(make_float2(v.x, v.y));
    o[2 * i + 1] = __float22bfloat162_rn(make_float2(v.z, v.w));
}

// ---- p1: gathered MFMA GEMM, LDS-staged W, 4-plane partials ---------
union ABFrag { short8 s8; __hip_bfloat162 h2[4]; };

__global__ __launch_bounds__(BLOCK) void p1_mfma(
    const float* __restrict__ w,
    const int*   __restrict__ idx,
    const __hip_bfloat16* __restrict__ xb,
    float*       __restrict__ partial)
{
    // 64 KB: per wave a 16 KB slab = [8 steps][2 halves][64 lanes][16 B]
    __shared__ float smem[4 * 4096];

    const int wave = (int)threadIdx.x >> 6;
    const int lane = (int)threadIdx.x & 63;
    const int quad = lane >> 4;
    const int m    = lane & 15;

    const int rt   = blockIdx.x % RT16;          // r-tile
    const int q    = blockIdx.x / RT16;          // plane 0..3
    const int ks   = q * 4 + wave;               // 0..15
    const int kofs = ks * KCHUNK;

    const int r   = rt * 16 + m;
    const int rc  = (r < REMAINED) ? r : (REMAINED - 1);  // padded rows:
    const int row = idx[rc];                              // masked in p2

    // post all 16 W DMAs (16 KB/wave) - zero VGPR in-flight cost
    const float* wp    = w + (size_t)row * D_MODEL + kofs + quad * 8;
    float*       lbase = &smem[wave * 4096];
#pragma unroll
    for (int s = 0; s < KSTEPS; ++s) {
#pragma unroll
        for (int h = 0; h < 2; ++h)
            GLD_LDS(wp + s * 32 + h * 4, lbase + (s * 2 + h) * 256);
    }

    // hoist B-fragment loads (xb is L2-resident) into the DMA wait window
    const short8* xp0 = (const short8*)(xb + (size_t)m * D_MODEL + kofs) + quad;
    const short8* xp1 = (const short8*)(xb + (size_t)(m + 16) * D_MODEL + kofs) + quad;
    short8 b0[KSTEPS], b1[KSTEPS];
#pragma unroll
    for (int s = 0; s < KSTEPS; ++s) { b0[s] = xp0[s * 4]; b1[s] = xp1[s * 4]; }

    __syncthreads();   // s_waitcnt vmcnt(0) + barrier: all DMA data landed

    floatx4 acc0 = {0.f, 0.f, 0.f, 0.f};
    floatx4 acc1 = {0.f, 0.f, 0.f, 0.f};
    const float4* lf4 = (const float4*)lbase;
#pragma unroll
    for (int s = 0; s < KSTEPS; ++s) {
        const float4 a0 = lf4[(s * 2 + 0) * 64 + lane];   // j = 0..3
        const float4 a1 = lf4[(s * 2 + 1) * 64 + lane];   // j = 4..7
        ABFrag af;
        af.h2[0] = __float22bfloat162_rn(make_float2(a0.x, a0.y));
        af.h2[1] = __float22bfloat162_rn(make_float2(a0.z, a0.w));
        af.h2[2] = __float22bfloat162_rn(make_float2(a1.x, a1.y));
        af.h2[3] = __float22bfloat162_rn(make_float2(a1.z, a1.w));
        acc0 = __builtin_amdgcn_mfma_f32_16x16x32_bf16(af.s8, b0[s], acc0, 0, 0, 0);
        acc1 = __builtin_amdgcn_mfma_f32_16x16x32_bf16(af.s8, b1[s], acc1, 0, 0, 0);
    }

    // intra-block reduce: 4 ks-waves -> one plane write
    __syncthreads();                       // waves done reading their slabs
    float4* red = (float4*)smem;           // [wave][32 b][4 quad] = 8 KB
    red[wave * 128 + m * 4 + quad]        =
        make_float4(acc0[0], acc0[1], acc0[2], acc0[3]);
    red[wave * 128 + (m + 16) * 4 + quad] =
        make_float4(acc1[0], acc1[1], acc1[2], acc1[3]);
    __syncthreads();

    const int t = (int)threadIdx.x;
    if (t < 128) {                         // t = b*4 + qd
        const float4 s0 = red[t], s1 = red[128 + t];
        const float4 s2 = red[256 + t], s3 = red[384 + t];
        const float4 sum = make_float4(s0.x + s1.x + s2.x + s3.x,
                                       s0.y + s1.y + s2.y + s3.y,
                                       s0.z + s1.z + s2.z + s3.z,
                                       s0.w + s1.w + s2.w + s3.w);
        const int b  = t >> 2;
        const int qd = t & 3;
        float* dst = partial +
            ((size_t)(q * BATCH + b) * RSLOTS + rt * 16 + qd * 4);
        *(float4*)dst = sum;
    }
}

// ---- p2: reduce 4 planes, masked write ------------------------------
#define GRID2  ((BATCH * (RSLOTS / 4)) / BLOCK)      // 32*1104/256 = 138

__global__ __launch_bounds__(BLOCK) void p2_reduce(
    const float* __restrict__ partial,
    float*       __restrict__ out)
{
    const int g  = blockIdx.x * BLOCK + threadIdx.x;
    const int b  = g / (RSLOTS / 4);
    const int r4 = g % (RSLOTS / 4);

    const float4* p = (const float4*)partial + ((size_t)b * (RSLOTS / 4) + r4);

    float4 s = make_float4(0.f, 0.f, 0.f, 0.f);
#pragma unroll
    for (int q = 0; q < QSPLIT; ++q) {
        const float4 v = p[(size_t)q * BATCH * (RSLOTS / 4)];
        s.x += v.x; s.y += v.y; s.z += v.z; s.w += v.w;
    }

    const int r0 = r4 * 4;
    float* o = out + (size_t)b * REMAINED;
    if (r0 + 3 < REMAINED) {
        *(float4*)(o + r0) = s;
    } else {
        if (r0 + 0 < REMAINED) o[r0 + 0] = s.x;
        if (r0 + 1 < REMAINED) o[r0 + 1] = s.y;
        if (r0 + 2 < REMAINED) o[r0 + 2] = s.z;
        if (r0 + 3 < REMAINED) o[r0 + 3] = s.w;
    }
}

extern "C" void kernel_launch(void* const* d_in, const int* in_sizes, int n_in,
                              void* d_out, int out_size, void* d_ws, size_t ws_size,
                              hipStream_t stream) {
    const float* x   = (const float*)d_in[0];
    const float* w   = (const float*)d_in[1];
    const int*   idx = (const int*)d_in[2];
    float*       out = (float*)d_out;

    __hip_bfloat16* xb      = (__hip_bfloat16*)d_ws;
    float*          partial = (float*)((char*)d_ws + PART_OFF);

    p0_cvt   <<<XB_ELEMS / 4 / BLOCK, BLOCK, 0, stream>>>(x, xb);  // 128 blk
    p1_mfma  <<<GRID1, BLOCK, 0, stream>>>(w, idx, xb, partial);
    p2_reduce<<<GRID2, BLOCK, 0, stream>>>(partial, out);
}